// Round 5
// baseline (455.911 us; speedup 1.0000x reference)
//
#include <hip/hip_runtime.h>
#include <hip/hip_bf16.h>
#include <stdint.h>

using bf16 = __hip_bfloat16;
typedef __attribute__((ext_vector_type(8))) short short8;
typedef __attribute__((ext_vector_type(4))) float floatx4;

#define DL3 32768      // 32^3
#define BATCH 256
#define NK 1024        // 32*32

// Swizzle for the LDS state S: element (v, n) lives at S[v*1024 + swz(n)].
// Swaps bits 3-4 of n by XOR with bits 6-7 -> A-frag ds_read_b128 is 2-way
// bank-aliased (free, m136) instead of 4/8-way.
__device__ __forceinline__ int swz(int n) {
  return (n & ~24) | ((((n >> 3) ^ (n >> 6)) & 3) << 3);
}

// nodeT[i][n][v*32+u] = node[i][u*32+v][n]  (fp32 -> bf16)  [R1-verified]
__global__ __launch_bounds__(256) void prep_nodes(const float* __restrict__ nodes, bf16* __restrict__ dst) {
  int id = blockIdx.x;
  int nb = id & 31, kb = (id >> 5) & 31, i = id >> 10;
  const float* src = nodes + (size_t)i * 1048576;
  bf16* d = dst + (size_t)i * 1048576;
  __shared__ float tile[32][33];
  int t = threadIdx.x;
#pragma unroll
  for (int it = 0; it < 4; ++it) {
    int u = (t >> 5) + it * 8, j = t & 31;
    tile[u][j] = src[(size_t)(u * 32 + kb) * 1024 + nb * 32 + j];
  }
  __syncthreads();
#pragma unroll
  for (int it = 0; it < 4; ++it) {
    int j = (t >> 5) + it * 8, u = t & 31;
    d[(size_t)(nb * 32 + j) * 1024 + kb * 32 + u] = __float2bfloat16(tile[u][j]);
  }
}

// Persistent fused kernel: one block per batch element; state S (32x1024 bf16)
// lives in LDS across all 6 contraction steps.
// Step GEMM: C[f][n] = sum_{k=v*32+u} S(v, f*32+u) * nodeT[step][n][k]
// A-frags from LDS (swizzled, read-only during K-loop -> NO barriers in K-loop);
// B-frags direct global->VGPR, 1-deep register double-buffer (partial vmcnt waits).
__global__ __launch_bounds__(512, 2) void entangler_fused(
    const float* __restrict__ x, const bf16* __restrict__ nodeT,
    const float* __restrict__ bias, float* __restrict__ out) {
  __shared__ bf16 S[32 * 1024];   // 64 KB
  const int b = blockIdx.x;
  const int t = threadIdx.x;
  const int lane = t & 63;
  const int lane16 = lane & 15, quad = lane >> 4;
  const int w = t >> 6;           // wave 0..7, owns n in [w*128, w*128+128)

  // ---- init S from x:  S(v, f*32+u) = x[b][u][v][f]  (fp32 -> bf16) ----
  {
    const float4* xb4 = (const float4*)(x + (size_t)b * DL3);
#pragma unroll
    for (int c = 0; c < 16; ++c) {
      float4 vl = xb4[c * 512 + t];          // coalesced 16B/lane
      int g0 = (c * 512 + t) * 4;
      const float* pv = (const float*)&vl;
#pragma unroll
      for (int e = 0; e < 4; ++e) {
        int g = g0 + e;
        int u = g >> 10, v = (g >> 5) & 31, f = g & 31;
        S[v * 1024 + swz(f * 32 + u)] = __float2bfloat16(pv[e]);
      }
    }
  }
  __syncthreads();

  // A-frag slot offset: for m = i*16+lane16, slot = quad ^ ((m>>1)&3);
  // i*16 contributes 8 mod-4 == 0, so slot is i-independent.
  const int sa = ((quad ^ ((lane16 >> 1) & 3)) << 3);

  for (int step = 0; step < 6; ++step) {
    const bf16* Bl = nodeT + (size_t)step * (NK * NK)
                   + (size_t)(w * 128 + lane16) * NK + quad * 8;

    floatx4 acc[2][8];
#pragma unroll
    for (int i = 0; i < 2; ++i)
#pragma unroll
      for (int j = 0; j < 8; ++j)
        acc[i][j] = (floatx4){0.f, 0.f, 0.f, 0.f};

    short8 bcur[8], bnxt[8];
#pragma unroll
    for (int j = 0; j < 8; ++j)
      bcur[j] = *(const short8*)(Bl + j * 16 * NK);

#pragma unroll 2
    for (int kv = 0; kv < 32; ++kv) {
      const int kvn = (kv + 1) & 31;    // last iter: harmless redundant load
#pragma unroll
      for (int j = 0; j < 8; ++j)
        bnxt[j] = *(const short8*)(Bl + j * 16 * NK + kvn * 32);

      short8 af0 = *(const short8*)(S + kv * 1024 + lane16 * 32 + sa);
      short8 af1 = *(const short8*)(S + kv * 1024 + (16 + lane16) * 32 + sa);
#pragma unroll
      for (int j = 0; j < 8; ++j) {
        acc[0][j] = __builtin_amdgcn_mfma_f32_16x16x32_bf16(af0, bcur[j], acc[0][j], 0, 0, 0);
        acc[1][j] = __builtin_amdgcn_mfma_f32_16x16x32_bf16(af1, bcur[j], acc[1][j], 0, 0, 0);
      }
#pragma unroll
      for (int j = 0; j < 8; ++j) bcur[j] = bnxt[j];
    }

    __syncthreads();   // all waves done reading S for this step

    if (step < 5) {
      // write C back into S: C row f becomes next step's v; col n = f'*32+u
#pragma unroll
      for (int i = 0; i < 2; ++i)
#pragma unroll
        for (int j = 0; j < 8; ++j)
#pragma unroll
          for (int r = 0; r < 4; ++r) {
            int v = i * 16 + quad * 4 + r;          // C/D: row = quad*4+reg (m89)
            int n = w * 128 + j * 16 + lane16;      // C/D: col = lane16
            S[v * 1024 + swz(n)] = __float2bfloat16(acc[i][j][r]);
          }
      __syncthreads();   // S ready for next step
    } else {
      // final epilogue: bias + relu, straight to global
      float* ob = out + (size_t)b * DL3;
#pragma unroll
      for (int i = 0; i < 2; ++i)
#pragma unroll
        for (int j = 0; j < 8; ++j)
#pragma unroll
          for (int r = 0; r < 4; ++r) {
            int row = i * 16 + quad * 4 + r;
            int col = w * 128 + j * 16 + lane16;
            float vv = acc[i][j][r] + bias[row * 1024 + col];
            ob[(size_t)row * 1024 + col] = fmaxf(vv, 0.f);
          }
    }
  }
}

extern "C" void kernel_launch(void* const* d_in, const int* in_sizes, int n_in,
                              void* d_out, int out_size, void* d_ws, size_t ws_size,
                              hipStream_t stream) {
  const float* x     = (const float*)d_in[0];   // (256, 32768) fp32
  const float* nodes = (const float*)d_in[1];   // (6, 32,32,32,32) fp32
  const float* bias  = (const float*)d_in[2];   // (32768,) fp32
  float* out = (float*)d_out;                   // (256, 32768) fp32

  bf16* nodeT = (bf16*)d_ws;                    // 12 MB

  prep_nodes<<<dim3(6 * 1024), dim3(256), 0, stream>>>(nodes, nodeT);
  entangler_fused<<<dim3(BATCH), dim3(512), 0, stream>>>(x, nodeT, bias, out);
}

// Round 6
// 388.941 us; speedup vs baseline: 1.1722x; 1.1722x over previous
//
#include <hip/hip_runtime.h>
#include <hip/hip_bf16.h>
#include <stdint.h>

using bf16 = __hip_bfloat16;
typedef __attribute__((ext_vector_type(8))) short short8;
typedef __attribute__((ext_vector_type(4))) float floatx4;

#define DL3 32768      // 32^3
#define BATCH 256
#define NK 1024        // 32*32

// ============================================================================
// Fragment-linear layouts (the whole point of this round):
//
// A' (state, 16MB bf16): A'(m = bx*128 + mg*16 + lane16, k = kv*32 + quad*8 + e)
//   flat = ((bx*8 + mg)*32 + kv)*512 + (quad*16 + lane16)*8 + e
//   -> a wave's af[i] load (fixed bx,mg,kv) is ONE contiguous 1KB dwordx4 load.
//
// B' (nodes, 2MB/node):  B'(n = ny*128 + ng*16 + lane16, k = kv*32 + quad*8 + e)
//   flat = ((ny*8 + ng)*32 + kv)*512 + (quad*16 + lane16)*8 + e
//   value = Bt[k][n] = node[u*32+v][n] with k = v*32+u   [R1-verified transform]
//
// Chain rule [R1-verified]: C(m=(b,f), n=(f',u')) becomes
//   A_next(m' = b*32+f', k' = f*32+u')  ->  same bx, mg'=(b&3)*2+(f'>>4),
//   kv'=f, lane16'=f'&15, quad'=u'>>3, e'=u'&7.
// ============================================================================

// One prep kernel: x -> A'0 and nodes -> B' (both fp32 -> bf16).
// Reads coalesced float4; writes scattered bf16 (small total, L2 merges).
__global__ __launch_bounds__(256) void prep(const float* __restrict__ x,
                                            const float* __restrict__ nodes,
                                            bf16* __restrict__ A0,
                                            bf16* __restrict__ Bp) {
  const int tid = blockIdx.x * 256 + threadIdx.x;   // grid 1024 -> 262144 threads
  const float4* x4 = (const float4*)x;
#pragma unroll
  for (int c = 0; c < 8; ++c) {
    int idx = c * 262144 + tid;                     // 2,097,152 float4s of x
    float4 val = x4[idx];
    int g = idx * 4;                                // x[b][u][v][f]
    int b = g >> 15, u = (g >> 10) & 31, v = (g >> 5) & 31, f0 = g & 31;
    const float* pv = (const float*)&val;
#pragma unroll
    for (int e2 = 0; e2 < 4; ++e2) {
      int f = f0 + e2;                              // A0(m=b*32+f, k=v*32+u)
      int addr = (((b >> 2) * 8 + (b & 3) * 2 + (f >> 4)) * 32 + v) * 512
               + ((u >> 3) * 16 + (f & 15)) * 8 + (u & 7);
      A0[addr] = __float2bfloat16(pv[e2]);
    }
  }
  const float4* n4 = (const float4*)nodes;
#pragma unroll
  for (int c = 0; c < 6; ++c) {
    int idx = c * 262144 + tid;                     // 1,572,864 float4s of nodes
    float4 val = n4[idx];
    int g = idx * 4;                                // node[i][row=u*32+v][n]
    int i = g >> 20, row = (g >> 10) & 1023, n0 = g & 1023;
    int u = row >> 5, v = row & 31;
    const float* pv = (const float*)&val;
#pragma unroll
    for (int e2 = 0; e2 < 4; ++e2) {
      int n = n0 + e2;                              // B'(n, k=v*32+u)
      int addr = (((n >> 7) * 8 + ((n >> 4) & 7)) * 32 + v) * 512
               + ((u >> 3) * 16 + (n & 15)) * 8 + (u & 7);
      Bp[(size_t)i * 1048576 + addr] = __float2bfloat16(pv[e2]);
    }
  }
}

// Barrier-free register GEMM. Block = 4 waves, block tile 128(M)x128(N),
// wave tile 64x64. NO LDS, NO __syncthreads: fragments load straight
// global->VGPR as contiguous 1KB dwordx4 (8 loads + 16 MFMA per kv),
// 2-deep register ring -> partial vmcnt waits (AITER-style), never a drain.
// bid mapping: bx = bid&63, ny = bid>>6 -> blocks sharing an A-slab share bid%8
// (same XCD under round-robin) for L2 locality.
template <bool FINAL>
__global__ __launch_bounds__(256, 2) void entangler_gemm(
    const bf16* __restrict__ Ae, const bf16* __restrict__ Be,
    bf16* __restrict__ Cn, float* __restrict__ Cf, const float* __restrict__ bias) {
  const int t = threadIdx.x;
  const int lane = t & 63;
  const int lane16 = lane & 15, quad = lane >> 4;
  const int w = t >> 6;
  const int bx = blockIdx.x & 63;
  const int ny = blockIdx.x >> 6;
  const int mh = (w >> 1);            // m-half 0/1 (waves 0,1 share A -> L1 hit)
  const int nh = (w & 1);             // n-half 0/1 (waves 0,2 share B)

  const bf16* pA[4];
  const bf16* pB[4];
#pragma unroll
  for (int i = 0; i < 4; ++i)
    pA[i] = Ae + (size_t)((bx * 8 + mh * 4 + i) * 32) * 512 + lane * 8;
#pragma unroll
  for (int j = 0; j < 4; ++j)
    pB[j] = Be + (size_t)((ny * 8 + nh * 4 + j) * 32) * 512 + lane * 8;

  floatx4 acc[4][4];
#pragma unroll
  for (int i = 0; i < 4; ++i)
#pragma unroll
    for (int j = 0; j < 4; ++j)
      acc[i][j] = (floatx4){0.f, 0.f, 0.f, 0.f};

  short8 a_[3][4], b_[3][4];
#pragma unroll
  for (int s = 0; s < 2; ++s)
#pragma unroll
    for (int i = 0; i < 4; ++i) {
      a_[s][i] = *(const short8*)(pA[i] + s * 512);
      b_[s][i] = *(const short8*)(pB[i] + s * 512);
    }

#pragma unroll
  for (int kv = 0; kv < 32; ++kv) {
    const int kp = kv + 2;
    if (kp < 32) {
      const int sl = kp % 3;
#pragma unroll
      for (int i = 0; i < 4; ++i) {
        a_[sl][i] = *(const short8*)(pA[i] + kp * 512);
        b_[sl][i] = *(const short8*)(pB[i] + kp * 512);
      }
    }
    const int s = kv % 3;
#pragma unroll
    for (int i = 0; i < 4; ++i)
#pragma unroll
      for (int j = 0; j < 4; ++j)
        acc[i][j] = __builtin_amdgcn_mfma_f32_16x16x32_bf16(a_[s][i], b_[s][j], acc[i][j], 0, 0, 0);
  }

  // Epilogue. C/D layout: col = lane&15, row = quad*4 + reg  [m89-verified]
#pragma unroll
  for (int i = 0; i < 4; ++i) {
#pragma unroll
    for (int j = 0; j < 4; ++j) {
#pragma unroll
      for (int r = 0; r < 4; ++r) {
        int m = bx * 128 + (mh * 4 + i) * 16 + quad * 4 + r;
        int n = ny * 128 + (nh * 4 + j) * 16 + lane16;
        if (FINAL) {
          float v = acc[i][j][r] + bias[(m & 31) * 1024 + n];
          Cf[(size_t)m * 1024 + n] = fmaxf(v, 0.f);
        } else {
          // write straight into next step's fragment-linear A'
          int f = m & 31, fp = n >> 5, up = n & 31;
          int mg = ((m >> 5) & 3) * 2 + (fp >> 4);
          int addr = ((bx * 8 + mg) * 32 + f) * 512
                   + ((up >> 3) * 16 + (fp & 15)) * 8 + (up & 7);
          Cn[addr] = __float2bfloat16(acc[i][j][r]);
        }
      }
    }
  }
}

extern "C" void kernel_launch(void* const* d_in, const int* in_sizes, int n_in,
                              void* d_out, int out_size, void* d_ws, size_t ws_size,
                              hipStream_t stream) {
  const float* x     = (const float*)d_in[0];   // (256, 32768) fp32
  const float* nodes = (const float*)d_in[1];   // (6, 32,32,32,32) fp32
  const float* bias  = (const float*)d_in[2];   // (32768,) fp32
  float* out = (float*)d_out;                   // (256, 32768) fp32

  // ws layout: A0 16MB | A1 16MB | B' 12MB  => 44MB
  bf16* A0 = (bf16*)d_ws;
  bf16* A1 = A0 + (size_t)BATCH * DL3;
  bf16* Bp = A1 + (size_t)BATCH * DL3;

  prep<<<dim3(1024), dim3(256), 0, stream>>>(x, nodes, A0, Bp);

  dim3 grid(512), blk(256);
  entangler_gemm<false><<<grid, blk, 0, stream>>>(A0, Bp + (size_t)0 * 1048576, A1, nullptr, nullptr);
  entangler_gemm<false><<<grid, blk, 0, stream>>>(A1, Bp + (size_t)1 * 1048576, A0, nullptr, nullptr);
  entangler_gemm<false><<<grid, blk, 0, stream>>>(A0, Bp + (size_t)2 * 1048576, A1, nullptr, nullptr);
  entangler_gemm<false><<<grid, blk, 0, stream>>>(A1, Bp + (size_t)3 * 1048576, A0, nullptr, nullptr);
  entangler_gemm<false><<<grid, blk, 0, stream>>>(A0, Bp + (size_t)4 * 1048576, A1, nullptr, nullptr);
  entangler_gemm<true ><<<grid, blk, 0, stream>>>(A1, Bp + (size_t)5 * 1048576, nullptr, out, bias);
}

// Round 7
// 323.580 us; speedup vs baseline: 1.4090x; 1.2020x over previous
//
#include <hip/hip_runtime.h>
#include <hip/hip_bf16.h>
#include <stdint.h>

using bf16 = __hip_bfloat16;
typedef __attribute__((ext_vector_type(8))) short short8;
typedef __attribute__((ext_vector_type(4))) float floatx4;

#define DL3 32768      // 32^3
#define BATCH 256

// ============================================================================
// Fragment-linear layouts [R6-verified correct]:
//   A'(m,k): flat = ((m>>4)*32 + (k>>5))*512 + ((k>>3)&3)*128 + (m&15)*8 + (k&7)
//   B'(n,k): same formula with n for m.  K = v*32+u, value = node[u*32+v][n].
//   Chain:   C(m,n) -> A'_next(m' = (m>>5)*32 + (n>>5), k' = (m&31)*32 + (n&31))
// A wave's 16x32 fragment (fixed m-group, kv) is ONE contiguous 1KB chunk.
// ============================================================================

__device__ __forceinline__ void load16(const void* g, void* l) {
  __builtin_amdgcn_global_load_lds((const __attribute__((address_space(1))) void*)g,
                                   (__attribute__((address_space(3))) void*)l,
                                   16, 0, 0);
}

// prep_x: block (b,v): x[b][u][v][f] -> A0 fragment-linear. Coalesced both sides.
__global__ __launch_bounds__(256) void prep_x(const float* __restrict__ x, bf16* __restrict__ A0) {
  const int b = blockIdx.x >> 5, v = blockIdx.x & 31;
  __shared__ float tile[32][33];            // [u][f]
  const int t = threadIdx.x;
  const float* xb = x + (size_t)b * DL3 + v * 32;
#pragma unroll
  for (int p = 0; p < 4; ++p) {
    int u = (t >> 5) + p * 8, f = t & 31;
    tile[u][f] = xb[u * 1024 + f];          // 128B per 32 lanes, coalesced
  }
  __syncthreads();
  const int idx = t * 2;                    // element pair within a 512-el chunk
  const int u = ((idx >> 7) << 3) | (idx & 7);
  const int fl = (idx >> 3) & 15;
#pragma unroll
  for (int h = 0; h < 2; ++h) {             // m-group (f>>4)
    size_t base = ((size_t)(b * 2 + h) * 32 + v) * 512;
    int f = h * 16 + fl;
    A0[base + idx]     = __float2bfloat16(tile[u][f]);
    A0[base + idx + 1] = __float2bfloat16(tile[u + 1][f]);   // adjacent 2B -> merged
  }
}

// prep_b: block (i, v, n-quarter): node[i][u*32+v][n] -> B' fragment-linear.
__global__ __launch_bounds__(256) void prep_b(const float* __restrict__ nodes, bf16* __restrict__ Bp) {
  const int id = blockIdx.x;
  const int nq = id & 3, v = (id >> 2) & 31, i = id >> 7;
  __shared__ float tile[32][260];           // [u][nl], nl in [0,256)
  const int t = threadIdx.x;
  const float* src = nodes + (size_t)i * 1048576 + (size_t)v * 1024 + nq * 256;
#pragma unroll
  for (int p = 0; p < 8; ++p) {
    int lin = p * 256 + t;                  // float4 index over 32x64 f4 tile
    int u = lin >> 6, nl4 = (lin & 63) * 4;
    float4 val = *(const float4*)(src + (size_t)u * 32768 + nl4);
    tile[u][nl4 + 0] = val.x; tile[u][nl4 + 1] = val.y;
    tile[u][nl4 + 2] = val.z; tile[u][nl4 + 3] = val.w;
  }
  __syncthreads();
  bf16* dst = Bp + (size_t)i * 1048576;
  const int idx = t * 2;
  const int u = ((idx >> 7) << 3) | (idx & 7);
  const int l16 = (idx >> 3) & 15;
#pragma unroll
  for (int grp = 0; grp < 16; ++grp) {      // 16 n-groups of 16 in this quarter
    size_t base = ((size_t)(nq * 16 + grp) * 32 + v) * 512;
    dst[base + idx]     = __float2bfloat16(tile[u][grp * 16 + l16]);
    dst[base + idx + 1] = __float2bfloat16(tile[u + 1][grp * 16 + l16]);
  }
}

// One contraction step. Block = 8 waves (512 thr), grid (16 msplit, 16 ntile).
// B n-slab (64 n x 1024 k = 128 KB) staged to LDS ONCE (one barrier total);
// A streams direct global->VGPR as contiguous 1KB dwordx4 fragments with a
// 1-deep register double-buffer. ZERO barriers in the K-loop -> no vmcnt(0)
// drain anywhere. All 8 waves broadcast the same B-frags from LDS.
// Blocks sharing an A-slab share blockIdx%8 -> same XCD -> A' L2-local.
template <bool FINAL>
__global__ __launch_bounds__(512, 2) void step_gemm(
    const bf16* __restrict__ Ae, const bf16* __restrict__ Be,
    bf16* __restrict__ Cn, float* __restrict__ Cf, const float* __restrict__ bias) {
  extern __shared__ bf16 sB[];              // 65536 els = 128 KB
  const int t = threadIdx.x;
  const int lane = t & 63;
  const int lane16 = lane & 15, quad = lane >> 4;
  const int w = t >> 6;
  const int msplit = blockIdx.x;            // 0..15 : m-range of 512 rows
  const int ntile  = blockIdx.y;            // 0..15 : n-range of 64 cols

  const bf16* Bsrc = Be + (size_t)ntile * 65536;   // contiguous B' slab
#pragma unroll
  for (int p = 0; p < 16; ++p)
    load16(Bsrc + (size_t)(p * 512 + t) * 8, sB + (size_t)(p * 512 + t) * 8);
  __syncthreads();                          // the ONLY barrier

  const int M0 = msplit * 512 + w * 64;     // wave's 64-row m-chunk
  const int grpA = M0 >> 4;
  const bf16* pA[4];
#pragma unroll
  for (int i = 0; i < 4; ++i)
    pA[i] = Ae + (size_t)(grpA + i) * 16384 + lane * 8;

  floatx4 acc[4][4];
#pragma unroll
  for (int i = 0; i < 4; ++i)
#pragma unroll
    for (int j = 0; j < 4; ++j)
      acc[i][j] = (floatx4){0.f, 0.f, 0.f, 0.f};

  short8 a_[2][4];
#pragma unroll
  for (int i = 0; i < 4; ++i)
    a_[0][i] = *(const short8*)(pA[i]);

#pragma unroll
  for (int kv = 0; kv < 32; ++kv) {
    if (kv + 1 < 32) {
#pragma unroll
      for (int i = 0; i < 4; ++i)
        a_[(kv + 1) & 1][i] = *(const short8*)(pA[i] + (kv + 1) * 512);
    }
    short8 bf_[4];
#pragma unroll
    for (int j = 0; j < 4; ++j)             // 2-way bank aliasing = free
      bf_[j] = *(const short8*)(sB + (size_t)(j * 32 + kv) * 512 + lane * 8);
    const int s = kv & 1;
#pragma unroll
    for (int i = 0; i < 4; ++i)
#pragma unroll
      for (int j = 0; j < 4; ++j)
        acc[i][j] = __builtin_amdgcn_mfma_f32_16x16x32_bf16(a_[s][i], bf_[j], acc[i][j], 0, 0, 0);
  }

  // Epilogue. C/D layout: col = lane&15, row = quad*4 + reg  [m89-verified]
  const int N0 = ntile * 64;
#pragma unroll
  for (int i = 0; i < 4; ++i) {
#pragma unroll
    for (int j = 0; j < 4; ++j) {
#pragma unroll
      for (int r = 0; r < 4; ++r) {
        int m = M0 + i * 16 + quad * 4 + r;
        int n = N0 + j * 16 + lane16;
        if (FINAL) {
          float v = acc[i][j][r] + bias[(m & 31) * 1024 + n];
          Cf[(size_t)m * 1024 + n] = fmaxf(v, 0.f);
        } else {
          // write straight into next step's fragment-linear A' [R6-verified]
          int f = m & 31, fp = n >> 5, up = n & 31;
          size_t addr = ((size_t)((m >> 5) * 2 + (n >> 9)) * 32 + f) * 512
                      + ((up >> 3) * 16 + (fp & 15)) * 8 + (up & 7);
          Cn[addr] = __float2bfloat16(acc[i][j][r]);
        }
      }
    }
  }
}

extern "C" void kernel_launch(void* const* d_in, const int* in_sizes, int n_in,
                              void* d_out, int out_size, void* d_ws, size_t ws_size,
                              hipStream_t stream) {
  const float* x     = (const float*)d_in[0];   // (256, 32768) fp32
  const float* nodes = (const float*)d_in[1];   // (6, 32,32,32,32) fp32
  const float* bias  = (const float*)d_in[2];   // (32768,) fp32
  float* out = (float*)d_out;                   // (256, 32768) fp32

  // ws layout: A0 16MB | A1 16MB | B' 12MB  => 44MB
  bf16* A0 = (bf16*)d_ws;
  bf16* A1 = A0 + (size_t)BATCH * DL3;
  bf16* Bp = A1 + (size_t)BATCH * DL3;

  // allow 128 KB dynamic LDS (host-side attribute set; graph-capture safe)
  hipFuncSetAttribute(reinterpret_cast<const void*>(step_gemm<false>),
                      hipFuncAttributeMaxDynamicSharedMemorySize, 131072);
  hipFuncSetAttribute(reinterpret_cast<const void*>(step_gemm<true>),
                      hipFuncAttributeMaxDynamicSharedMemorySize, 131072);

  prep_x<<<dim3(BATCH * 32), dim3(256), 0, stream>>>(x, A0);
  prep_b<<<dim3(768), dim3(256), 0, stream>>>(nodes, Bp);

  dim3 grid(16, 16), blk(512);
  step_gemm<false><<<grid, blk, 131072, stream>>>(A0, Bp + (size_t)0 * 1048576, A1, nullptr, nullptr);
  step_gemm<false><<<grid, blk, 131072, stream>>>(A1, Bp + (size_t)1 * 1048576, A0, nullptr, nullptr);
  step_gemm<false><<<grid, blk, 131072, stream>>>(A0, Bp + (size_t)2 * 1048576, A1, nullptr, nullptr);
  step_gemm<false><<<grid, blk, 131072, stream>>>(A1, Bp + (size_t)3 * 1048576, A0, nullptr, nullptr);
  step_gemm<false><<<grid, blk, 131072, stream>>>(A0, Bp + (size_t)4 * 1048576, A1, nullptr, nullptr);
  step_gemm<true ><<<grid, blk, 131072, stream>>>(A1, Bp + (size_t)5 * 1048576, nullptr, out, bias);
}